// Round 15
// baseline (3506.123 us; speedup 1.0000x reference)
//
#include <hip/hip_runtime.h>

// RNN: xp = x@Wx^T + b (GEMM, bf16 MFMA), then 512-step scan
// h_t = tanh(xp_t + h_{t-1}@Wh^T).
// Round 15 = r11 exchange (proven) with the LDS reduce + barrier DELETED:
// each wave owns 16 j x full K=1024 (no k-split -> no partials -> no LDS).
// Weights streamed from L2 inside the MFMA loop (r14 proved LDS is worse;
// r11 proved L2 streaming is off the critical path). Poll: 32 coalesced
// dwordx4 packs (8 asm blocks of 4, bases stride 4096B), epoch code in
// every dword's 2 LSBs, whole-burst retry with s_sleep(1) throttle.
// Producer side byte-identical to r11: pack publish via agent-scope store,
// deferred out-store, distance-2 xp parity prefetch.

typedef unsigned short u16;
typedef unsigned u32;
typedef unsigned long long u64;
typedef __attribute__((ext_vector_type(4))) float f32x4;
typedef __attribute__((ext_vector_type(8))) short bf16x8;
typedef __attribute__((ext_vector_type(4))) u32 u32x4;

__device__ __forceinline__ u16 f2bf(float f) {
  unsigned u = __builtin_bit_cast(unsigned, f);
  unsigned r = (u + 0x7fffu + ((u >> 16) & 1u)) >> 16;  // RTN-even
  return (u16)r;
}

// bf16 with bit0 forced to `bit` (<=1 ULP error: trunc or trunc+1)
__device__ __forceinline__ u16 f2bf_par(float f, unsigned bit) {
  unsigned rt = __builtin_bit_cast(unsigned, f) >> 16;  // truncate
  return (u16)(((rt & 1u) == bit) ? rt : rt + 1u);
}

// tanh via single exp: 1 - 2/(e^{2x}+1)
__device__ __forceinline__ float fast_tanh(float x) {
  float e = __expf(2.0f * x);
  return 1.0f - 2.0f / (e + 1.0f);
}

__device__ __forceinline__ void async_cp16(u16* lds, const u16* g) {
  __builtin_amdgcn_global_load_lds(
      (const __attribute__((address_space(1))) unsigned int*)g,
      (__attribute__((address_space(3))) unsigned int*)lds, 16, 0, 0);
}

// ---------------- conversion kernels ----------------

__global__ __launch_bounds__(256) void conv_x_kernel(const float* __restrict__ in,
                                                     u16* __restrict__ outb) {
  const size_t i = (size_t)blockIdx.x * 256 + threadIdx.x;  // 8-elem chunk id
  const float4* p = (const float4*)(in + (i << 3));
  float4 a = p[0], b = p[1];
  bf16x8 v;
  v[0] = (short)f2bf(a.x); v[1] = (short)f2bf(a.y);
  v[2] = (short)f2bf(a.z); v[3] = (short)f2bf(a.w);
  v[4] = (short)f2bf(b.x); v[5] = (short)f2bf(b.y);
  v[6] = (short)f2bf(b.z); v[7] = (short)f2bf(b.w);
  *(bf16x8*)(outb + (i << 3)) = v;
}

__global__ __launch_bounds__(256) void conv_w_kernel(const float* __restrict__ W,
                                                     u16* __restrict__ Wx,
                                                     u16* __restrict__ Wh) {
  const int i = blockIdx.x * 256 + threadIdx.x;  // 8-elem chunk id, 2048/row
  const int j = i >> 8;          // row 0..1023
  const int c = (i & 255) << 3;  // col 0..2040
  const float4* p = (const float4*)(W + (size_t)j * 2048 + c);
  float4 a = p[0], b = p[1];
  bf16x8 v;
  v[0] = (short)f2bf(a.x); v[1] = (short)f2bf(a.y);
  v[2] = (short)f2bf(a.z); v[3] = (short)f2bf(a.w);
  v[4] = (short)f2bf(b.x); v[5] = (short)f2bf(b.y);
  v[6] = (short)f2bf(b.z); v[7] = (short)f2bf(b.w);
  u16* dst = (c < 1024) ? (Wx + (size_t)j * 1024 + c)
                        : (Wh + (size_t)j * 1024 + (c - 1024));
  *(bf16x8*)dst = v;
}

// ---------------- Phase 1: xp GEMM (m97 structure) ----------------

__global__ __launch_bounds__(256, 2) void gemm_xp(const u16* __restrict__ A,
                                                  const u16* __restrict__ B,
                                                  const float* __restrict__ bias,
                                                  float* __restrict__ C) {
  const int bid = blockIdx.x;                    // 2048 blocks
  const int swz = (bid & 7) * 256 + (bid >> 3);  // XCD-aware swizzle (nwg%8==0)
  const int m0 = (swz >> 3) << 7;
  const int n0 = (swz & 7) << 7;
  const int tid = threadIdx.x;
  const int lane = tid & 63;
  const int wv = tid >> 6;
  const int mw = (wv >> 1) << 6;
  const int nw = (wv & 1) << 6;

  __shared__ __align__(16) u16 Alds[128 * 32];
  __shared__ __align__(16) u16 Blds[128 * 32];

  f32x4 acc[4][4] = {};

  for (int kt = 0; kt < 32; ++kt) {
    const int k0 = kt << 5;
#pragma unroll
    for (int i = 0; i < 2; ++i) {
      const int off = (i << 11) + (tid << 3);
      const int row = off >> 5;
      const int col = off & 31;
      async_cp16(&Alds[off], A + (size_t)(m0 + row) * 1024 + k0 + col);
      async_cp16(&Blds[off], B + (size_t)(n0 + row) * 1024 + k0 + col);
    }
    __syncthreads();  // drains vmcnt -> LDS ready
    bf16x8 af[4], bf[4];
#pragma unroll
    for (int mi = 0; mi < 4; ++mi)
      af[mi] = *(const bf16x8*)&Alds[((mw + (mi << 4) + (lane & 15)) << 5) +
                                     ((lane >> 4) << 3)];
#pragma unroll
    for (int ni = 0; ni < 4; ++ni)
      bf[ni] = *(const bf16x8*)&Blds[((nw + (ni << 4) + (lane & 15)) << 5) +
                                     ((lane >> 4) << 3)];
#pragma unroll
    for (int mi = 0; mi < 4; ++mi)
#pragma unroll
      for (int ni = 0; ni < 4; ++ni)
        acc[mi][ni] = __builtin_amdgcn_mfma_f32_16x16x32_bf16(
            af[mi], bf[ni], acc[mi][ni], 0, 0, 0);
    __syncthreads();
  }

  float bv[4];
#pragma unroll
  for (int ni = 0; ni < 4; ++ni)
    bv[ni] = bias[n0 + nw + (ni << 4) + (lane & 15)];
#pragma unroll
  for (int mi = 0; mi < 4; ++mi) {
#pragma unroll
    for (int r = 0; r < 4; ++r) {
      const int row = m0 + mw + (mi << 4) + ((lane >> 4) << 2) + r;
      float* cp = C + (size_t)row * 1024 + n0 + nw + (lane & 15);
#pragma unroll
      for (int ni = 0; ni < 4; ++ni) cp[ni << 4] = acc[mi][ni][r] + bv[ni];
    }
  }
}

// ---------------- Phase 2: recurrent scan (wave-independent, no LDS) ------
// WG (g=wg&3, wloc=wg>>2): batches [16g,+16). Wave wv: j [64wloc+16wv,+16),
// FULL K=1024. Poll: 32 packs at unit (4kk+lhi), batch l16 -> Hs + kk*1024,
// 8 bases stride 4096. MFMA: acc[kk&3] (4-way dep-chain interleave),
// A-frag streamed from L2 per use. No barriers anywhere in the loop.

#define PB4(F0, F1, F2, F3, BASE)                                         \
  asm volatile("global_load_dwordx4 %0, %4, off sc0 sc1\n\t"              \
               "global_load_dwordx4 %1, %4, off offset:1024 sc0 sc1\n\t"  \
               "global_load_dwordx4 %2, %4, off offset:2048 sc0 sc1\n\t"  \
               "global_load_dwordx4 %3, %4, off offset:3072 sc0 sc1"      \
               : "=&v"(F0), "=&v"(F1), "=&v"(F2), "=&v"(F3)               \
               : "v"(BASE)                                                \
               : "memory");

#define CK(V)                                                              \
  ok &= (u32)((((V)[0] & 1u) | ((((V)[0] >> 16) & 1u) << 1)) == e);        \
  ok &= (u32)((((V)[2] & 1u) | ((((V)[2] >> 16) & 1u) << 1)) == e);

#define MF(IDX, Q)                                                         \
  {                                                                        \
    union { u32x4 u; bf16x8 v; } u_;                                      \
    u_.u = Q;                                                              \
    const bf16x8 a_ = *(const bf16x8*)(wp + ((IDX) << 5));                 \
    acc[(IDX) & 3] = __builtin_amdgcn_mfma_f32_16x16x32_bf16(              \
        a_, u_.v, acc[(IDX) & 3], 0, 0, 0);                                \
  }

__global__ __launch_bounds__(256) void rnn_scan(float* __restrict__ out,
                                                const u16* __restrict__ Wh,
                                                char* __restrict__ Hb) {
  const int wg = blockIdx.x;   // 0..63
  const int g = wg & 3;        // group (16 batches)
  const int wloc = wg >> 2;    // 0..15 (64-j slice)
  const int tid = threadIdx.x;
  const int lane = tid & 63;
  const int wv = tid >> 6;     // 0..3 (16-j tile owner)
  const int l16 = lane & 15;
  const int lhi = lane >> 4;

  const int j0w = (wloc << 6) + (wv << 4);   // wave's 16-j base
  const u16* wp = Wh + (size_t)(j0w + l16) * 1024 + (lhi << 3);

  const int b = (g << 4) + l16;
  const int hread = (g << 15) + (lhi << 8) + (l16 << 4);  // + kk*1024
  const int jq = (wloc << 4) + (wv << 2) + lhi;
  const int hwrite = (g << 15) + ((jq >> 1) << 8) + (l16 << 4) + ((jq & 1) << 3);
  const int j0 = jq << 2;
  float* pout = out + ((size_t)b << 19) + j0;  // b*512*1024 + j

  f32x4 xpA = __builtin_nontemporal_load((const f32x4*)pout);           // t=0
  f32x4 xpB = __builtin_nontemporal_load((const f32x4*)(pout + 1024));  // t=1
  f32x4 hvP = {0.f, 0.f, 0.f, 0.f};

#pragma unroll 1
  for (int t = 0; t < 512; ++t) {
    f32x4 acc[4] = {};
    if (t > 0) {
      const u32 e = 1u + ((((u32)t - 1u) >> 1) & 1u);
      const char* Hs = Hb + (((t - 1) & 1) << 17) + hread;
      u32x4 q0, q1, q2, q3, q4, q5, q6, q7, q8, q9, q10, q11, q12, q13, q14,
          q15, q16, q17, q18, q19, q20, q21, q22, q23, q24, q25, q26, q27,
          q28, q29, q30, q31;
      while (true) {
        PB4(q0, q1, q2, q3, Hs)
        PB4(q4, q5, q6, q7, Hs + 4096)
        PB4(q8, q9, q10, q11, Hs + 8192)
        PB4(q12, q13, q14, q15, Hs + 12288)
        PB4(q16, q17, q18, q19, Hs + 16384)
        PB4(q20, q21, q22, q23, Hs + 20480)
        PB4(q24, q25, q26, q27, Hs + 24576)
        PB4(q28, q29, q30, q31, Hs + 28672)
        asm volatile("s_waitcnt vmcnt(0)" ::: "memory");
        u32 ok = 1u;
        CK(q0) CK(q1) CK(q2) CK(q3) CK(q4) CK(q5) CK(q6) CK(q7)
        CK(q8) CK(q9) CK(q10) CK(q11) CK(q12) CK(q13) CK(q14) CK(q15)
        CK(q16) CK(q17) CK(q18) CK(q19) CK(q20) CK(q21) CK(q22) CK(q23)
        CK(q24) CK(q25) CK(q26) CK(q27) CK(q28) CK(q29) CK(q30) CK(q31)
        if (__all((int)ok)) break;
        __builtin_amdgcn_s_sleep(1);  // throttle spin traffic at the MALL
      }
      // deferred out-store of h(t-1): ages a full step before next poll
      __builtin_nontemporal_store(hvP,
                                  (f32x4*)(pout + ((size_t)(t - 1) << 10)));
      MF(0, q0) MF(1, q1) MF(2, q2) MF(3, q3)
      MF(4, q4) MF(5, q5) MF(6, q6) MF(7, q7)
      MF(8, q8) MF(9, q9) MF(10, q10) MF(11, q11)
      MF(12, q12) MF(13, q13) MF(14, q14) MF(15, q15)
      MF(16, q16) MF(17, q17) MF(18, q18) MF(19, q19)
      MF(20, q20) MF(21, q21) MF(22, q22) MF(23, q23)
      MF(24, q24) MF(25, q25) MF(26, q26) MF(27, q27)
      MF(28, q28) MF(29, q29) MF(30, q30) MF(31, q31)
    }

    const f32x4 s = (acc[0] + acc[1]) + (acc[2] + acc[3]);
    const f32x4 xp = (t & 1) ? xpB : xpA;
    const float h0 = fast_tanh(xp[0] + s[0]);
    const float h1 = fast_tanh(xp[1] + s[1]);
    const float h2 = fast_tanh(xp[2] + s[2]);
    const float h3 = fast_tanh(xp[3] + s[3]);

    // publish: epoch code in the 2 LSBs of every dword (tear-detecting)
    const u32 code = 1u + (((u32)t >> 1) & 1u);
    const u32 c0b = code & 1u, c1b = (code >> 1) & 1u;
    const u64 pack = (u64)f2bf_par(h0, c0b) | ((u64)f2bf_par(h1, c1b) << 16) |
                     ((u64)f2bf_par(h2, c0b) << 32) |
                     ((u64)f2bf_par(h3, c1b) << 48);
    __hip_atomic_store((u64*)(Hb + ((t & 1) << 17) + hwrite), pack,
                       __ATOMIC_RELAXED, __HIP_MEMORY_SCOPE_AGENT);

    // xp prefetch, distance 2, loaded directly into the parity register
    if (t + 2 < 512) {
      const f32x4* src = (const f32x4*)(pout + ((size_t)(t + 2) << 10));
      if (t & 1)
        xpB = __builtin_nontemporal_load(src);
      else
        xpA = __builtin_nontemporal_load(src);
    }
    hvP[0] = h0; hvP[1] = h1; hvP[2] = h2; hvP[3] = h3;
  }
  __builtin_nontemporal_store(hvP, (f32x4*)(pout + ((size_t)511 << 10)));
}

// ---------------- launcher ----------------

extern "C" void kernel_launch(void* const* d_in, const int* in_sizes, int n_in,
                              void* d_out, int out_size, void* d_ws,
                              size_t ws_size, hipStream_t stream) {
  const float* x = (const float*)d_in[0];     // [64][512][1024]
  const float* W = (const float*)d_in[1];     // [1024][2048]
  const float* bias = (const float*)d_in[2];  // [1024]
  float* out = (float*)d_out;                 // [64][512][1024]

  char* ws = (char*)d_ws;
  u16* xb = (u16*)ws;                           // 67,108,864 B
  u16* Wxb = (u16*)(ws + 67108864);             //  2,097,152 B
  u16* Whb = (u16*)(ws + 69206016);             //  2,097,152 B
  char* Hbuf = (char*)(ws + 71303168);          //    262,144 B (2 x 128KB)

  (void)hipMemsetAsync(Hbuf, 0, 262144, stream);  // all dword codes -> 0
  conv_x_kernel<<<16384, 256, 0, stream>>>(x, xb);
  conv_w_kernel<<<1024, 256, 0, stream>>>(W, Wxb, Whb);
  gemm_xp<<<2048, 256, 0, stream>>>(xb, Wxb, bias, out);
  rnn_scan<<<64, 256, 0, stream>>>(out, Whb, Hbuf);
}

// Round 16
// 1037.974 us; speedup vs baseline: 3.3779x; 3.3779x over previous
//
#include <hip/hip_runtime.h>

// RNN: xp = x@Wx^T + b (GEMM, bf16 MFMA, fp32 x converted in-staging),
// then 512-step scan h_t = tanh(xp_t + h_{t-1}@Wh^T).
// Round 16 = round-11 champion restored verbatim (947us scan), with the
// conv_x dispatch deleted: gemm_xp reads x fp32 and converts during
// A-staging (r13-proven path). Scan: 4 groups x 16 WGs x 4 waves; wave =
// k-slice 256; coalesced exchange ([g][joct][batch][16B], 16B unit = 8
// consecutive j x 1 batch); epoch code (1+((t>>1)&1)) in every dword's 2
// LSBs (tear-detecting); agent-scope ops; lgkm-only barrier; deferred
// out-store; distance-2 xp parity prefetch; weights streamed from L2
// (measured optimal vs registers r4/r5 and vs LDS r14).

typedef unsigned short u16;
typedef unsigned u32;
typedef unsigned long long u64;
typedef __attribute__((ext_vector_type(4))) float f32x4;
typedef __attribute__((ext_vector_type(8))) short bf16x8;
typedef __attribute__((ext_vector_type(4))) u32 u32x4;

__device__ __forceinline__ u16 f2bf(float f) {
  unsigned u = __builtin_bit_cast(unsigned, f);
  unsigned r = (u + 0x7fffu + ((u >> 16) & 1u)) >> 16;  // RTN-even
  return (u16)r;
}

// bf16 with bit0 forced to `bit` (<=1 ULP error: trunc or trunc+1)
__device__ __forceinline__ u16 f2bf_par(float f, unsigned bit) {
  unsigned rt = __builtin_bit_cast(unsigned, f) >> 16;  // truncate
  return (u16)(((rt & 1u) == bit) ? rt : rt + 1u);
}

// tanh via single exp: 1 - 2/(e^{2x}+1)
__device__ __forceinline__ float fast_tanh(float x) {
  float e = __expf(2.0f * x);
  return 1.0f - 2.0f / (e + 1.0f);
}

__device__ __forceinline__ void async_cp16(u16* lds, const u16* g) {
  __builtin_amdgcn_global_load_lds(
      (const __attribute__((address_space(1))) unsigned int*)g,
      (__attribute__((address_space(3))) unsigned int*)lds, 16, 0, 0);
}

// ---------------- conv_w ----------------

__global__ __launch_bounds__(256) void conv_w_kernel(const float* __restrict__ W,
                                                     u16* __restrict__ Wx,
                                                     u16* __restrict__ Wh) {
  const int i = blockIdx.x * 256 + threadIdx.x;  // 8-elem chunk id, 2048/row
  const int j = i >> 8;          // row 0..1023
  const int c = (i & 255) << 3;  // col 0..2040
  const float4* p = (const float4*)(W + (size_t)j * 2048 + c);
  float4 a = p[0], b = p[1];
  bf16x8 v;
  v[0] = (short)f2bf(a.x); v[1] = (short)f2bf(a.y);
  v[2] = (short)f2bf(a.z); v[3] = (short)f2bf(a.w);
  v[4] = (short)f2bf(b.x); v[5] = (short)f2bf(b.y);
  v[6] = (short)f2bf(b.z); v[7] = (short)f2bf(b.w);
  u16* dst = (c < 1024) ? (Wx + (size_t)j * 1024 + c)
                        : (Wh + (size_t)j * 1024 + (c - 1024));
  *(bf16x8*)dst = v;
}

// ---------------- Phase 1: xp GEMM (m97 structure, fp32-A fused conv) ----

__global__ __launch_bounds__(256, 2) void gemm_xp(const float* __restrict__ x,
                                                  const u16* __restrict__ B,
                                                  const float* __restrict__ bias,
                                                  float* __restrict__ C) {
  const int bid = blockIdx.x;                    // 2048 blocks
  const int swz = (bid & 7) * 256 + (bid >> 3);  // XCD-aware swizzle (nwg%8==0)
  const int m0 = (swz >> 3) << 7;
  const int n0 = (swz & 7) << 7;
  const int tid = threadIdx.x;
  const int lane = tid & 63;
  const int wv = tid >> 6;
  const int mw = (wv >> 1) << 6;
  const int nw = (wv & 1) << 6;

  __shared__ __align__(16) u16 Alds[128 * 32];
  __shared__ __align__(16) u16 Blds[128 * 32];

  f32x4 acc[4][4] = {};

  for (int kt = 0; kt < 32; ++kt) {
    const int k0 = kt << 5;
#pragma unroll
    for (int i = 0; i < 2; ++i) {
      const int off = (i << 11) + (tid << 3);
      const int row = off >> 5;
      const int col = off & 31;
      // A: x fp32 -> bf16 inline (replaces the conv_x dispatch; r13-proven)
      const float* ap = x + (size_t)(m0 + row) * 1024 + k0 + col;
      float4 a0 = *(const float4*)ap;
      float4 a1 = *(const float4*)(ap + 4);
      bf16x8 av;
      av[0] = (short)f2bf(a0.x); av[1] = (short)f2bf(a0.y);
      av[2] = (short)f2bf(a0.z); av[3] = (short)f2bf(a0.w);
      av[4] = (short)f2bf(a1.x); av[5] = (short)f2bf(a1.y);
      av[6] = (short)f2bf(a1.z); av[7] = (short)f2bf(a1.w);
      *(bf16x8*)&Alds[off] = av;
      async_cp16(&Blds[off], B + (size_t)(n0 + row) * 1024 + k0 + col);
    }
    __syncthreads();  // drains vmcnt + lgkm -> LDS ready
    bf16x8 af[4], bf[4];
#pragma unroll
    for (int mi = 0; mi < 4; ++mi)
      af[mi] = *(const bf16x8*)&Alds[((mw + (mi << 4) + (lane & 15)) << 5) +
                                     ((lane >> 4) << 3)];
#pragma unroll
    for (int ni = 0; ni < 4; ++ni)
      bf[ni] = *(const bf16x8*)&Blds[((nw + (ni << 4) + (lane & 15)) << 5) +
                                     ((lane >> 4) << 3)];
#pragma unroll
    for (int mi = 0; mi < 4; ++mi)
#pragma unroll
      for (int ni = 0; ni < 4; ++ni)
        acc[mi][ni] = __builtin_amdgcn_mfma_f32_16x16x32_bf16(
            af[mi], bf[ni], acc[mi][ni], 0, 0, 0);
    __syncthreads();
  }

  float bv[4];
#pragma unroll
  for (int ni = 0; ni < 4; ++ni)
    bv[ni] = bias[n0 + nw + (ni << 4) + (lane & 15)];
#pragma unroll
  for (int mi = 0; mi < 4; ++mi) {
#pragma unroll
    for (int r = 0; r < 4; ++r) {
      const int row = m0 + mw + (mi << 4) + ((lane >> 4) << 2) + r;
      float* cp = C + (size_t)row * 1024 + n0 + nw + (lane & 15);
#pragma unroll
      for (int ni = 0; ni < 4; ++ni) cp[ni << 4] = acc[mi][ni][r] + bv[ni];
    }
  }
}

// ---------------- Phase 2: recurrent scan (r11 verbatim) ----------------
// H buffer: 2 x [g4][joct128][batch16][16B]; joct = j>>3. Consumer wave wv
// (k-slice [256wv,+256)): frag kk at byte (g<<15)+((32wv+4kk+lhi)<<8)+(l16<<4)
// -> 8 x dwordx4, kk-stride 1024B (two 4096B base regs for the offset range).
// Producer lane: jq = 16wloc+4wv+lhi; 8B pack at ((jq>>1)<<8)+(l16<<4)+((jq&1)<<3).

__global__ __launch_bounds__(256) void rnn_scan(float* __restrict__ out,
                                                const u16* __restrict__ Wh,
                                                char* __restrict__ Hb) {
  const int wg = blockIdx.x;   // 0..63
  const int g = wg & 3;        // group (16 batches)
  const int wloc = wg >> 2;    // 0..15 (64-j slice)
  const int tid = threadIdx.x;
  const int lane = tid & 63;
  const int wv = tid >> 6;     // 0..3 (k-slice AND j-tile owner)
  const int l16 = lane & 15;
  const int lhi = lane >> 4;

  __shared__ __align__(16) f32x4 red[2][4][4][64];  // 32KB dbuf

  // A-frags: af[jt][kk] = Wh[64wloc+16jt+l16][256wv + 32kk + 8lhi .. +8]
  bf16x8 af[4][8];
  {
    const u16* wp =
        Wh + (size_t)((wloc << 6) + l16) * 1024 + (wv << 8) + (lhi << 3);
#pragma unroll
    for (int jt = 0; jt < 4; ++jt)
#pragma unroll
      for (int kk = 0; kk < 8; ++kk)
        af[jt][kk] = *(const bf16x8*)(wp + (jt << 14) + (kk << 5));
  }

  const int b = (g << 4) + l16;
  const int hread = (g << 15) + (((wv << 5) + lhi) << 8) + (l16 << 4);
  const int jq = (wloc << 4) + (wv << 2) + lhi;
  const int hwrite = (g << 15) + ((jq >> 1) << 8) + (l16 << 4) + ((jq & 1) << 3);
  const int j0 = jq << 2;
  float* pout = out + ((size_t)b << 19) + j0;  // b*512*1024 + j

  f32x4 xpA = __builtin_nontemporal_load((const f32x4*)pout);           // t=0
  f32x4 xpB = __builtin_nontemporal_load((const f32x4*)(pout + 1024));  // t=1
  f32x4 hvP = {0.f, 0.f, 0.f, 0.f};

#pragma unroll 1
  for (int t = 0; t < 512; ++t) {
    f32x4 acc[4] = {};
    if (t > 0) {
      const u32 e = 1u + ((((u32)t - 1u) >> 1) & 1u);
      const char* Hs = Hb + (((t - 1) & 1) << 17) + hread;
      const char* Hs2 = Hs + 4096;
      u32x4 f0, f1, f2, f3, f4, f5, f6, f7;
      while (true) {
        asm volatile(
            "global_load_dwordx4 %0, %8, off sc0 sc1\n\t"
            "global_load_dwordx4 %1, %8, off offset:1024 sc0 sc1\n\t"
            "global_load_dwordx4 %2, %8, off offset:2048 sc0 sc1\n\t"
            "global_load_dwordx4 %3, %8, off offset:3072 sc0 sc1\n\t"
            "global_load_dwordx4 %4, %9, off sc0 sc1\n\t"
            "global_load_dwordx4 %5, %9, off offset:1024 sc0 sc1\n\t"
            "global_load_dwordx4 %6, %9, off offset:2048 sc0 sc1\n\t"
            "global_load_dwordx4 %7, %9, off offset:3072 sc0 sc1\n\t"
            "s_waitcnt vmcnt(0)"
            : "=&v"(f0), "=&v"(f1), "=&v"(f2), "=&v"(f3), "=&v"(f4),
              "=&v"(f5), "=&v"(f6), "=&v"(f7)
            : "v"(Hs), "v"(Hs2)
            : "memory");
        u32 ok = 1u;
#pragma unroll
        for (int d = 0; d < 4; ++d) {
          ok &= (u32)(((f0[d] & 1u) | (((f0[d] >> 16) & 1u) << 1)) == e);
          ok &= (u32)(((f1[d] & 1u) | (((f1[d] >> 16) & 1u) << 1)) == e);
          ok &= (u32)(((f2[d] & 1u) | (((f2[d] >> 16) & 1u) << 1)) == e);
          ok &= (u32)(((f3[d] & 1u) | (((f3[d] >> 16) & 1u) << 1)) == e);
          ok &= (u32)(((f4[d] & 1u) | (((f4[d] >> 16) & 1u) << 1)) == e);
          ok &= (u32)(((f5[d] & 1u) | (((f5[d] >> 16) & 1u) << 1)) == e);
          ok &= (u32)(((f6[d] & 1u) | (((f6[d] >> 16) & 1u) << 1)) == e);
          ok &= (u32)(((f7[d] & 1u) | (((f7[d] >> 16) & 1u) << 1)) == e);
        }
        if (__all((int)ok)) break;
      }
      // deferred out-store of h(t-1): ages a full step before next poll
      __builtin_nontemporal_store(hvP,
                                  (f32x4*)(pout + ((size_t)(t - 1) << 10)));
      union { u32x4 u; bf16x8 v; } c[8];
      c[0].u = f0; c[1].u = f1; c[2].u = f2; c[3].u = f3;
      c[4].u = f4; c[5].u = f5; c[6].u = f6; c[7].u = f7;
#pragma unroll
      for (int kk = 0; kk < 8; ++kk)
#pragma unroll
        for (int jt = 0; jt < 4; ++jt)
          acc[jt] = __builtin_amdgcn_mfma_f32_16x16x32_bf16(af[jt][kk], c[kk].v,
                                                            acc[jt], 0, 0, 0);
    }

    const int rb = t & 1;
#pragma unroll
    for (int jt = 0; jt < 4; ++jt) red[rb][wv][jt][lane] = acc[jt];
    // lgkm-only barrier: do NOT drain vmcnt (publish/out/xp stay in flight)
    asm volatile("s_waitcnt lgkmcnt(0)\n\ts_barrier" ::: "memory");

    f32x4 s = red[rb][0][wv][lane];
#pragma unroll
    for (int w = 1; w < 4; ++w) s += red[rb][w][wv][lane];

    const f32x4 xp = (t & 1) ? xpB : xpA;
    const float h0 = fast_tanh(xp[0] + s[0]);
    const float h1 = fast_tanh(xp[1] + s[1]);
    const float h2 = fast_tanh(xp[2] + s[2]);
    const float h3 = fast_tanh(xp[3] + s[3]);

    // publish: epoch code in the 2 LSBs of every dword (tear-detecting)
    const u32 code = 1u + (((u32)t >> 1) & 1u);
    const u32 c0b = code & 1u, c1b = (code >> 1) & 1u;
    const u64 pack = (u64)f2bf_par(h0, c0b) | ((u64)f2bf_par(h1, c1b) << 16) |
                     ((u64)f2bf_par(h2, c0b) << 32) |
                     ((u64)f2bf_par(h3, c1b) << 48);
    __hip_atomic_store((u64*)(Hb + ((t & 1) << 17) + hwrite), pack,
                       __ATOMIC_RELAXED, __HIP_MEMORY_SCOPE_AGENT);

    // xp prefetch, distance 2, loaded directly into the parity register
    if (t + 2 < 512) {
      const f32x4* src = (const f32x4*)(pout + ((size_t)(t + 2) << 10));
      if (t & 1)
        xpB = __builtin_nontemporal_load(src);
      else
        xpA = __builtin_nontemporal_load(src);
    }
    hvP[0] = h0; hvP[1] = h1; hvP[2] = h2; hvP[3] = h3;
  }
  __builtin_nontemporal_store(hvP, (f32x4*)(pout + ((size_t)511 << 10)));
}

// ---------------- launcher ----------------

extern "C" void kernel_launch(void* const* d_in, const int* in_sizes, int n_in,
                              void* d_out, int out_size, void* d_ws,
                              size_t ws_size, hipStream_t stream) {
  const float* x = (const float*)d_in[0];     // [64][512][1024]
  const float* W = (const float*)d_in[1];     // [1024][2048]
  const float* bias = (const float*)d_in[2];  // [1024]
  float* out = (float*)d_out;                 // [64][512][1024]

  char* ws = (char*)d_ws;
  u16* Wxb = (u16*)ws;                          // 2,097,152 B
  u16* Whb = (u16*)(ws + 2097152);              // 2,097,152 B
  char* Hbuf = (char*)(ws + 4194304);           //   262,144 B (2 x 128KB)

  (void)hipMemsetAsync(Hbuf, 0, 262144, stream);  // all dword codes -> 0
  conv_w_kernel<<<1024, 256, 0, stream>>>(W, Wxb, Whb);
  gemm_xp<<<2048, 256, 0, stream>>>(x, Wxb, bias, out);
  rnn_scan<<<64, 256, 0, stream>>>(out, Whb, Hbuf);
}